// Round 2
// baseline (857.526 us; speedup 1.0000x reference)
//
#include <hip/hip_runtime.h>
#include <hip/hip_bf16.h>

typedef __hip_bfloat16 bf16;

#define B_   4
#define S_   4096
#define D_   768
#define NH_  8
#define DK_  64
#define DV_  64
#define CH_  64              // chunk length
#define NCH_ (S_/CH_)        // 64 chunks
#define DECAY_ 0.95f
#define WSTR_  0.1f

__device__ __forceinline__ float b2f(bf16 v) { return __bfloat162float(v); }
__device__ __forceinline__ bf16  f2b(float v) { return __float2bfloat16(v); }

// ---- generic 4-element loaders / 1-element stores -------------------------
__device__ __forceinline__ void load4(const float* p, float f[4]) {
    const float4 v = *reinterpret_cast<const float4*>(p);
    f[0] = v.x; f[1] = v.y; f[2] = v.z; f[3] = v.w;
}
__device__ __forceinline__ void load4(const bf16* p, float f[4]) {
    const ushort4 v = *reinterpret_cast<const ushort4*>(p);
    union { unsigned u; float f; } c;
    c.u = (unsigned)v.x << 16; f[0] = c.f;
    c.u = (unsigned)v.y << 16; f[1] = c.f;
    c.u = (unsigned)v.z << 16; f[2] = c.f;
    c.u = (unsigned)v.w << 16; f[3] = c.f;
}
__device__ __forceinline__ void stc(float* p, float v) { *p = v; }
__device__ __forceinline__ void stc(bf16* p, float v)  { *p = f2b(v); }

// ---------------------------------------------------------------------------
// C = A @ B^T (+ optional X add), fp32 accumulate. A: MxK, B: NxK, X/C: MxN.
// Tile 64x64, BK=16, 256 threads, 4x4 per thread. M,N mult of 64; K mult of 16.
// ---------------------------------------------------------------------------
template<typename TA, typename TB, typename TC, int ADDX>
__global__ __launch_bounds__(256) void gemm_bt(const TA* __restrict__ A,
                                               const TB* __restrict__ Bm,
                                               const float* __restrict__ X,
                                               TC* __restrict__ C,
                                               int M, int N, int K) {
    __shared__ float As[16][65];   // As[k][m]
    __shared__ float Bs[16][65];   // Bs[k][n]
    const int bm = blockIdx.y * 64, bn = blockIdx.x * 64;
    const int tid = threadIdx.x;
    const int ty = tid >> 4, tx = tid & 15;
    float acc[4][4] = {};

    for (int k0 = 0; k0 < K; k0 += 16) {
        {
            const int m  = tid >> 2;
            const int kk = (tid & 3) * 4;
            float fa[4], fb[4];
            load4(A  + (size_t)(bm + m) * K + k0 + kk, fa);
            load4(Bm + (size_t)(bn + m) * K + k0 + kk, fb);
            #pragma unroll
            for (int i = 0; i < 4; i++) { As[kk + i][m] = fa[i]; Bs[kk + i][m] = fb[i]; }
        }
        __syncthreads();
        #pragma unroll
        for (int kk = 0; kk < 16; kk++) {
            float a[4], b[4];
            #pragma unroll
            for (int i = 0; i < 4; i++) a[i] = As[kk][ty * 4 + i];
            #pragma unroll
            for (int j = 0; j < 4; j++) b[j] = Bs[kk][tx * 4 + j];
            #pragma unroll
            for (int i = 0; i < 4; i++)
                #pragma unroll
                for (int j = 0; j < 4; j++) acc[i][j] += a[i] * b[j];
        }
        __syncthreads();
    }
    #pragma unroll
    for (int i = 0; i < 4; i++)
        #pragma unroll
        for (int j = 0; j < 4; j++) {
            const int m = bm + ty * 4 + i, n = bn + tx * 4 + j;
            float v = acc[i][j];
            if (ADDX) v += X[(size_t)m * N + n];
            stc(C + (size_t)m * N + n, v);
        }
}

// ---------------------------------------------------------------------------
// wgt[s][h] = 0.1 * sigmoid(x0[s,:] . w_gate[h,:])    (batch 0 only)
// ---------------------------------------------------------------------------
__global__ __launch_bounds__(64) void gate_kernel(const float* __restrict__ x,
                                                  const float* __restrict__ wg,
                                                  float* __restrict__ wgt) {
    const int s = blockIdx.x >> 3, h = blockIdx.x & 7;
    const int lane = threadIdx.x;
    const float* xr = x + (size_t)s * D_;
    const float* wr = wg + (size_t)h * D_;
    float sum = 0.f;
    for (int d = lane; d < D_; d += 64) sum += xr[d] * wr[d];
    #pragma unroll
    for (int off = 32; off; off >>= 1) sum += __shfl_down(sum, off);
    if (lane == 0) wgt[s * NH_ + h] = WSTR_ / (1.f + expf(-sum));
}

// ---------------------------------------------------------------------------
// lsums[n,h] = sum_{i<CH} 0.95^(CH-1-i) * w_i * k_i v_i^T   (64x64 fp32)
// ---------------------------------------------------------------------------
__global__ __launch_bounds__(256) void chunk_sums(const bf16* __restrict__ k0,
                                                  const bf16* __restrict__ v0,
                                                  const float* __restrict__ wgt,
                                                  float* __restrict__ lsums) {
    const int n = blockIdx.x, h = blockIdx.y;
    __shared__ float ks[CH_][65];
    __shared__ float vs[CH_][64];
    __shared__ float cw[CH_];
    const int tid = threadIdx.x;
    for (int e = tid; e < CH_ * 64; e += 256) {
        const int r = e >> 6, c = e & 63;
        const int t = n * CH_ + r;
        ks[r][c] = b2f(k0[(size_t)t * (NH_ * DK_) + h * DK_ + c]);
        vs[r][c] = b2f(v0[(size_t)t * (NH_ * DV_) + h * DV_ + c]);
    }
    if (tid < CH_) {
        const int t = n * CH_ + tid;
        cw[tid] = powf(DECAY_, (float)(CH_ - 1 - tid)) * wgt[t * NH_ + h];
    }
    __syncthreads();
    const int j = tid & 63, ig = tid >> 6;
    float acc[16] = {};
    for (int idx = 0; idx < CH_; idx++) {
        const float cv = cw[idx] * vs[idx][j];
        #pragma unroll
        for (int r = 0; r < 16; r++) acc[r] += ks[idx][ig * 16 + r] * cv;
    }
    float* out = lsums + ((size_t)(n * NH_ + h)) * (DK_ * DV_);
    #pragma unroll
    for (int r = 0; r < 16; r++) out[(ig * 16 + r) * 64 + j] = acc[r];
}

// ---------------------------------------------------------------------------
// states[n,h] = FW before chunk n:  FW_{n+1} = 0.95^CH * FW_n + lsums[n]
// ---------------------------------------------------------------------------
__global__ __launch_bounds__(256) void state_scan(const float* __restrict__ lsums,
                                                  float* __restrict__ states) {
    const int h = blockIdx.x >> 4;
    const int e = (blockIdx.x & 15) * 256 + threadIdx.x;   // 0..4095
    const float dC = powf(DECAY_, (float)CH_);
    float fw = 0.f;
    for (int n = 0; n < NCH_; n++) {
        const size_t idx = ((size_t)(n * NH_ + h)) * (DK_ * DV_) + e;
        states[idx] = fw;
        fw = dC * fw + lsums[idx];
    }
}

// ---------------------------------------------------------------------------
// retrieved[t][j] = 0.95^lt * (q_t @ FW)[j]
//                 + sum_{s<lt} 0.95^(lt-1-s)*w_s*(q_t.k_s) * v[s][j]
// grid (NCH_, NH_, B_), 256 threads.  LDS 56.75 KB (Amat aliases ks).
// ---------------------------------------------------------------------------
__global__ __launch_bounds__(256) void chunk_output(const bf16* __restrict__ q,
                                                    const bf16* __restrict__ k0,
                                                    const bf16* __restrict__ v0,
                                                    const float* __restrict__ wgt,
                                                    const float* __restrict__ states,
                                                    bf16* __restrict__ retr) {
    const int n = blockIdx.x, h = blockIdx.y, b = blockIdx.z;
    __shared__ float qs[CH_][64];    // broadcast reads only
    __shared__ float ksA[CH_][65];   // phase A: k rows; after: Amat[t][s]
    __shared__ bf16  vsb[CH_][64];
    __shared__ float FW[64][64];
    __shared__ float wloc[CH_];
    __shared__ float dpow[CH_];
    const int tid = threadIdx.x;
    const int t0 = n * CH_;

    for (int e = tid; e < CH_ * 64; e += 256) {
        const int r = e >> 6, c = e & 63;
        qs[r][c]  = b2f(q[((size_t)(b * S_ + t0 + r)) * (NH_ * DK_) + h * DK_ + c]);
        ksA[r][c] = b2f(k0[((size_t)(t0 + r)) * (NH_ * DK_) + h * DK_ + c]);
        vsb[r][c] = v0[((size_t)(t0 + r)) * (NH_ * DV_) + h * DV_ + c];
        FW[r][c]  = states[((size_t)(n * NH_ + h)) * (DK_ * DV_) + e];
    }
    if (tid < CH_) {
        wloc[tid] = wgt[(t0 + tid) * NH_ + h];
        dpow[tid] = powf(DECAY_, (float)tid);
    }
    __syncthreads();

    const int lane = tid & 63, tg = tid >> 6;   // tg uniform per wave
    // Phase A: raw scores acc[r] = q_{tg*16+r} . k_{lane}
    float acc[16] = {};
    for (int i = 0; i < 64; i++) {
        const float kb = ksA[lane][i];
        #pragma unroll
        for (int r = 0; r < 16; r++) acc[r] += qs[tg * 16 + r][i] * kb;
    }
    __syncthreads();   // all reads of ksA-as-k done; safe to overwrite with Amat
    #pragma unroll
    for (int r = 0; r < 16; r++) {
        const int t = tg * 16 + r;
        ksA[t][lane] = (lane < t) ? acc[r] * dpow[t - 1 - lane] * wloc[lane] : 0.f;
    }
    __syncthreads();
    // Phase B: out[t][j], j = lane
    {
        float o[16] = {};
        for (int i = 0; i < 64; i++) {
            const float fb = FW[i][lane];
            #pragma unroll
            for (int r = 0; r < 16; r++) o[r] += qs[tg * 16 + r][i] * fb;
        }
        #pragma unroll
        for (int r = 0; r < 16; r++) o[r] *= dpow[tg * 16 + r];
        for (int s = 0; s < CH_; s++) {
            const float vb = b2f(vsb[s][lane]);
            #pragma unroll
            for (int r = 0; r < 16; r++) o[r] += ksA[tg * 16 + r][s] * vb;
        }
        #pragma unroll
        for (int r = 0; r < 16; r++) {
            const int t = tg * 16 + r;
            retr[((size_t)(b * S_ + t0 + t)) * (NH_ * DV_) + h * DV_ + lane] = f2b(o[r]);
        }
    }
}

// ---------------------------------------------------------------------------
extern "C" void kernel_launch(void* const* d_in, const int* in_sizes, int n_in,
                              void* d_out, int out_size, void* d_ws, size_t ws_size,
                              hipStream_t stream) {
    const float* x  = (const float*)d_in[0];
    const float* wk = (const float*)d_in[1];
    const float* wv = (const float*)d_in[2];
    const float* wq = (const float*)d_in[3];
    const float* wg = (const float*)d_in[4];
    const float* wo = (const float*)d_in[5];
    float* out = (float*)d_out;

    char* w = (char*)d_ws;
    bf16*  qbuf   = (bf16*)(w);                                   // 16 MB
    bf16*  k0buf  = (bf16*)(w + (16ull << 20));                   // 4 MB
    bf16*  v0buf  = (bf16*)(w + (20ull << 20));                   // 4 MB
    float* wgt    = (float*)(w + (24ull << 20));                  // 128 KB
    float* states = (float*)(w + (24ull << 20) + (1ull << 17));   // 8 MB
    bf16*  retr   = (bf16*)(w + (33ull << 20));                   // 16 MB
    float* lsums  = (float*)retr;  // aliased: dead before retr is written

    const int MB = B_ * S_;  // 16384

    // projections (fp32 in, bf16 staging out)
    gemm_bt<float, float, bf16, 0><<<dim3(512 / 64, MB / 64), 256, 0, stream>>>(x, wq, nullptr, qbuf, MB, 512, D_);
    gemm_bt<float, float, bf16, 0><<<dim3(512 / 64, S_ / 64), 256, 0, stream>>>(x, wk, nullptr, k0buf, S_, 512, D_);
    gemm_bt<float, float, bf16, 0><<<dim3(512 / 64, S_ / 64), 256, 0, stream>>>(x, wv, nullptr, v0buf, S_, 512, D_);
    gate_kernel<<<S_ * NH_, 64, 0, stream>>>(x, wg, wgt);

    // chunked scan
    chunk_sums<<<dim3(NCH_, NH_), 256, 0, stream>>>(k0buf, v0buf, wgt, lsums);
    state_scan<<<NH_ * 16, 256, 0, stream>>>(lsums, states);
    chunk_output<<<dim3(NCH_, NH_, B_), 256, 0, stream>>>(qbuf, k0buf, v0buf, wgt, states, retr);

    // out = x + retrieved @ w_out^T   (fp32 out)
    gemm_bt<bf16, float, float, 1><<<dim3(D_ / 64, MB / 64), 256, 0, stream>>>(retr, wo, x, out, MB, D_, 512);
}

// Round 3
// 338.778 us; speedup vs baseline: 2.5312x; 2.5312x over previous
//
#include <hip/hip_runtime.h>
#include <hip/hip_bf16.h>

typedef __hip_bfloat16 bf16;
typedef __attribute__((ext_vector_type(8))) short   bf16x8;  // 8 bf16 = 4 VGPRs
typedef __attribute__((ext_vector_type(4))) float   f32x4;

#define B_   4
#define S_   4096
#define D_   768
#define NH_  8
#define DK_  64
#define DV_  64
#define CH_  64              // chunk length
#define NCH_ (S_/CH_)        // 64 chunks
#define DECAY_ 0.95f
#define WSTR_  0.1f

__device__ __forceinline__ float b2f(bf16 v) { return __bfloat162float(v); }
__device__ __forceinline__ bf16  f2b(float v) { return __float2bfloat16(v); }

// async global -> LDS, 16 bytes per lane; lds base must be wave-uniform,
// HW writes lane i at lds + i*16.
__device__ __forceinline__ void gl2lds16(const bf16* g, bf16* lds) {
    __builtin_amdgcn_global_load_lds(
        (const __attribute__((address_space(1))) void*)g,
        (__attribute__((address_space(3))) void*)lds, 16, 0, 0);
}

// ---------------------------------------------------------------------------
// fp32 -> bf16 cast, 4 elems/thread
// ---------------------------------------------------------------------------
__global__ __launch_bounds__(256) void cast_f2b(const float* __restrict__ src,
                                                bf16* __restrict__ dst, int n) {
    const int i = (blockIdx.x * 256 + threadIdx.x) * 4;
    if (i < n) {
        const float4 v = *reinterpret_cast<const float4*>(src + i);
        union { bf16 b[4]; ushort4 u; } t;
        t.b[0] = f2b(v.x); t.b[1] = f2b(v.y); t.b[2] = f2b(v.z); t.b[3] = f2b(v.w);
        *reinterpret_cast<ushort4*>(dst + i) = t.u;
    }
}

// ---------------------------------------------------------------------------
// MFMA GEMM: C = A @ B^T (+ optional fp32 X add). A: MxK bf16, B: NxK bf16.
// 128x128 tile, BK=32, 256 threads = 4 waves (2x2 of 64x64), 16 MFMA/wave/step.
// KV mode: blocks with blockIdx.x >= nb0 use B1/C1 (k+v fused dispatch).
// M,N mult of 128; K mult of 32.
// ---------------------------------------------------------------------------
template<typename TC, int ADDX, int KV>
__global__ __launch_bounds__(256) void gemm_mfma(const bf16* __restrict__ A,
                                                 const bf16* __restrict__ B0,
                                                 const bf16* __restrict__ B1,
                                                 const float* __restrict__ X,
                                                 TC* __restrict__ C0,
                                                 TC* __restrict__ C1,
                                                 int M, int N, int K, int nb0) {
    __shared__ bf16 As[128 * 32];
    __shared__ bf16 Bs[128 * 32];
    int bx = blockIdx.x;
    const bf16* Bm = B0;
    TC* C = C0;
    if (KV && bx >= nb0) { Bm = B1; C = C1; bx -= nb0; }
    const int bm = blockIdx.y * 128, bn = bx * 128;
    const int tid = threadIdx.x, lane = tid & 63, w = tid >> 6;
    const int quad = lane >> 4, l16 = lane & 15;
    const int wm = (w >> 1) * 64, wn = (w & 1) * 64;

    // staging geometry: wave w, call c covers LDS bytes [(w*2+c)*1024, +1024)
    int ro[2], ko[2];
    #pragma unroll
    for (int c = 0; c < 2; c++) {
        const int o = (w * 2 + c) * 1024 + lane * 16;   // byte offset in tile
        ro[c] = o >> 6;          // tile row (64 B per row of 32 bf16)
        ko[c] = (o & 63) >> 1;   // k element within BK
    }

    f32x4 acc[4][4] = {};

    for (int k0 = 0; k0 < K; k0 += 32) {
        #pragma unroll
        for (int c = 0; c < 2; c++) {
            bf16* lA = &As[(w * 2 + c) * 512];
            bf16* lB = &Bs[(w * 2 + c) * 512];
            gl2lds16(A  + (size_t)(bm + ro[c]) * K + k0 + ko[c], lA);
            gl2lds16(Bm + (size_t)(bn + ro[c]) * K + k0 + ko[c], lB);
        }
        __syncthreads();   // compiler emits vmcnt(0) drain before barrier
        bf16x8 af[4], bfr[4];
        #pragma unroll
        for (int t = 0; t < 4; t++) {
            af[t]  = *reinterpret_cast<const bf16x8*>(&As[(wm + t * 16 + l16) * 32 + quad * 8]);
            bfr[t] = *reinterpret_cast<const bf16x8*>(&Bs[(wn + t * 16 + l16) * 32 + quad * 8]);
        }
        #pragma unroll
        for (int mt = 0; mt < 4; mt++)
            #pragma unroll
            for (int nt = 0; nt < 4; nt++)
                acc[mt][nt] = __builtin_amdgcn_mfma_f32_16x16x32_bf16(
                    af[mt], bfr[nt], acc[mt][nt], 0, 0, 0);
        __syncthreads();
    }

    // epilogue: C/D layout col = lane&15, row = quad*4 + reg
    #pragma unroll
    for (int mt = 0; mt < 4; mt++)
        #pragma unroll
        for (int nt = 0; nt < 4; nt++)
            #pragma unroll
            for (int r = 0; r < 4; r++) {
                const int m = bm + wm + mt * 16 + quad * 4 + r;
                const int n = bn + wn + nt * 16 + l16;
                float v = acc[mt][nt][r];
                if (ADDX) v += X[(size_t)m * N + n];
                if (sizeof(TC) == 2) *(bf16*)&C[(size_t)m * N + n] = f2b(v);
                else                 *(float*)&C[(size_t)m * N + n] = v;
            }
}

// ---------------------------------------------------------------------------
// wgt[s][h] = 0.1 * sigmoid(x0[s,:] . w_gate[h,:])    (batch 0 only)
// ---------------------------------------------------------------------------
__global__ __launch_bounds__(64) void gate_kernel(const float* __restrict__ x,
                                                  const float* __restrict__ wg,
                                                  float* __restrict__ wgt) {
    const int s = blockIdx.x >> 3, h = blockIdx.x & 7;
    const int lane = threadIdx.x;
    const float* xr = x + (size_t)s * D_;
    const float* wr = wg + (size_t)h * D_;
    float sum = 0.f;
    for (int d = lane; d < D_; d += 64) sum += xr[d] * wr[d];
    #pragma unroll
    for (int off = 32; off; off >>= 1) sum += __shfl_down(sum, off);
    if (lane == 0) wgt[s * NH_ + h] = WSTR_ / (1.f + expf(-sum));
}

// ---------------------------------------------------------------------------
// lsums[n,h] = sum_{i<CH} 0.95^(CH-1-i) * w_i * k_i v_i^T   (64x64 fp32)
// ---------------------------------------------------------------------------
__global__ __launch_bounds__(256) void chunk_sums(const bf16* __restrict__ k0,
                                                  const bf16* __restrict__ v0,
                                                  const float* __restrict__ wgt,
                                                  float* __restrict__ lsums) {
    const int n = blockIdx.x, h = blockIdx.y;
    __shared__ float ks[CH_][65];
    __shared__ float vs[CH_][64];
    __shared__ float cw[CH_];
    const int tid = threadIdx.x;
    for (int e = tid; e < CH_ * 64; e += 256) {
        const int r = e >> 6, c = e & 63;
        const int t = n * CH_ + r;
        ks[r][c] = b2f(k0[(size_t)t * (NH_ * DK_) + h * DK_ + c]);
        vs[r][c] = b2f(v0[(size_t)t * (NH_ * DV_) + h * DV_ + c]);
    }
    if (tid < CH_) {
        const int t = n * CH_ + tid;
        cw[tid] = powf(DECAY_, (float)(CH_ - 1 - tid)) * wgt[t * NH_ + h];
    }
    __syncthreads();
    const int j = tid & 63, ig = tid >> 6;
    float acc[16] = {};
    for (int idx = 0; idx < CH_; idx++) {
        const float cv = cw[idx] * vs[idx][j];
        #pragma unroll
        for (int r = 0; r < 16; r++) acc[r] += ks[idx][ig * 16 + r] * cv;
    }
    float* out = lsums + ((size_t)(n * NH_ + h)) * (DK_ * DV_);
    #pragma unroll
    for (int r = 0; r < 16; r++) out[(ig * 16 + r) * 64 + j] = acc[r];
}

// ---------------------------------------------------------------------------
// states[n,h] = FW before chunk n:  FW_{n+1} = 0.95^CH * FW_n + lsums[n]
// ---------------------------------------------------------------------------
__global__ __launch_bounds__(256) void state_scan(const float* __restrict__ lsums,
                                                  float* __restrict__ states) {
    const int h = blockIdx.x >> 4;
    const int e = (blockIdx.x & 15) * 256 + threadIdx.x;   // 0..4095
    const float dC = powf(DECAY_, (float)CH_);
    float fw = 0.f;
    for (int n = 0; n < NCH_; n++) {
        const size_t idx = ((size_t)(n * NH_ + h)) * (DK_ * DV_) + e;
        states[idx] = fw;
        fw = dC * fw + lsums[idx];
    }
}

// ---------------------------------------------------------------------------
// retrieved[t][j] = 0.95^lt * (q_t @ FW)[j]
//                 + sum_{s<lt} 0.95^(lt-1-s)*w_s*(q_t.k_s) * v[s][j]
// grid (NCH_, NH_, B_), 256 threads.  LDS 56.75 KB (Amat aliases ks).
// ---------------------------------------------------------------------------
__global__ __launch_bounds__(256) void chunk_output(const bf16* __restrict__ q,
                                                    const bf16* __restrict__ k0,
                                                    const bf16* __restrict__ v0,
                                                    const float* __restrict__ wgt,
                                                    const float* __restrict__ states,
                                                    bf16* __restrict__ retr) {
    const int n = blockIdx.x, h = blockIdx.y, b = blockIdx.z;
    __shared__ float qs[CH_][64];    // broadcast reads only
    __shared__ float ksA[CH_][65];   // phase A: k rows; after: Amat[t][s]
    __shared__ bf16  vsb[CH_][64];
    __shared__ float FW[64][64];
    __shared__ float wloc[CH_];
    __shared__ float dpow[CH_];
    const int tid = threadIdx.x;
    const int t0 = n * CH_;

    for (int e = tid; e < CH_ * 64; e += 256) {
        const int r = e >> 6, c = e & 63;
        qs[r][c]  = b2f(q[((size_t)(b * S_ + t0 + r)) * (NH_ * DK_) + h * DK_ + c]);
        ksA[r][c] = b2f(k0[((size_t)(t0 + r)) * (NH_ * DK_) + h * DK_ + c]);
        vsb[r][c] = v0[((size_t)(t0 + r)) * (NH_ * DV_) + h * DV_ + c];
        FW[r][c]  = states[((size_t)(n * NH_ + h)) * (DK_ * DV_) + e];
    }
    if (tid < CH_) {
        wloc[tid] = wgt[(t0 + tid) * NH_ + h];
        dpow[tid] = powf(DECAY_, (float)tid);
    }
    __syncthreads();

    const int lane = tid & 63, tg = tid >> 6;   // tg uniform per wave
    // Phase A: raw scores acc[r] = q_{tg*16+r} . k_{lane}
    float acc[16] = {};
    for (int i = 0; i < 64; i++) {
        const float kb = ksA[lane][i];
        #pragma unroll
        for (int r = 0; r < 16; r++) acc[r] += qs[tg * 16 + r][i] * kb;
    }
    __syncthreads();   // all reads of ksA-as-k done; safe to overwrite with Amat
    #pragma unroll
    for (int r = 0; r < 16; r++) {
        const int t = tg * 16 + r;
        ksA[t][lane] = (lane < t) ? acc[r] * dpow[t - 1 - lane] * wloc[lane] : 0.f;
    }
    __syncthreads();
    // Phase B: out[t][j], j = lane
    {
        float o[16] = {};
        for (int i = 0; i < 64; i++) {
            const float fb = FW[i][lane];
            #pragma unroll
            for (int r = 0; r < 16; r++) o[r] += qs[tg * 16 + r][i] * fb;
        }
        #pragma unroll
        for (int r = 0; r < 16; r++) o[r] *= dpow[tg * 16 + r];
        for (int s = 0; s < CH_; s++) {
            const float vb = b2f(vsb[s][lane]);
            #pragma unroll
            for (int r = 0; r < 16; r++) o[r] += ksA[tg * 16 + r][s] * vb;
        }
        #pragma unroll
        for (int r = 0; r < 16; r++) {
            const int t = tg * 16 + r;
            retr[((size_t)(b * S_ + t0 + t)) * (NH_ * DV_) + h * DV_ + lane] = f2b(o[r]);
        }
    }
}

// ---------------------------------------------------------------------------
extern "C" void kernel_launch(void* const* d_in, const int* in_sizes, int n_in,
                              void* d_out, int out_size, void* d_ws, size_t ws_size,
                              hipStream_t stream) {
    const float* x  = (const float*)d_in[0];
    const float* wk = (const float*)d_in[1];
    const float* wv = (const float*)d_in[2];
    const float* wq = (const float*)d_in[3];
    const float* wg = (const float*)d_in[4];
    const float* wo = (const float*)d_in[5];
    float* out = (float*)d_out;

    const size_t MB1 = 1ull << 20;
    char* w = (char*)d_ws;
    bf16*  qbuf   = (bf16*)(w);                          // 16 MB
    bf16*  k0buf  = (bf16*)(w + 16 * MB1);               // 4 MB
    bf16*  v0buf  = (bf16*)(w + 20 * MB1);               // 4 MB
    float* wgt    = (float*)(w + 24 * MB1);              // 128 KB
    bf16*  wqb    = (bf16*)(w + 24 * MB1 + (128ull<<10));        // 768 KB
    bf16*  wkb    = (bf16*)(w + 24 * MB1 + (128ull<<10) + 1*786432);
    bf16*  wvb    = (bf16*)(w + 24 * MB1 + (128ull<<10) + 2*786432);
    bf16*  wob    = (bf16*)(w + 24 * MB1 + (128ull<<10) + 3*786432);
    char*  base2  = w + 24 * MB1 + (128ull<<10) + 4*786432;      // ~27.1 MB
    float* states = (float*)(base2);                      // 8 MB
    bf16*  retr   = (bf16*)(base2 + 8 * MB1);             // 16 MB
    float* lsums  = (float*)retr;                         // aliased (dead before retr)
    bf16*  xb     = (bf16*)(base2);                       // 24 MB, aliased over
                     // states+retr: xb dead before chunk_sums/state_scan write them

    const int MB = B_ * S_;  // 16384

    // casts (fp32 -> bf16)
    cast_f2b<<<12288, 256, 0, stream>>>(x,  xb,  MB * D_);
    cast_f2b<<<384,   256, 0, stream>>>(wq, wqb, 512 * D_);
    cast_f2b<<<384,   256, 0, stream>>>(wk, wkb, 512 * D_);
    cast_f2b<<<384,   256, 0, stream>>>(wv, wvb, 512 * D_);
    cast_f2b<<<384,   256, 0, stream>>>(wo, wob, D_ * 512);

    gate_kernel<<<S_ * NH_, 64, 0, stream>>>(x, wg, wgt);

    // projections (MFMA)
    gemm_mfma<bf16, 0, 0><<<dim3(512 / 128, MB / 128), 256, 0, stream>>>(
        xb, wqb, nullptr, nullptr, qbuf, nullptr, MB, 512, D_, 4);
    gemm_mfma<bf16, 0, 1><<<dim3(8, S_ / 128), 256, 0, stream>>>(
        xb, wkb, wvb, nullptr, k0buf, v0buf, S_, 512, D_, 4);

    // chunked scan
    chunk_sums<<<dim3(NCH_, NH_), 256, 0, stream>>>(k0buf, v0buf, wgt, lsums);
    state_scan<<<NH_ * 16, 256, 0, stream>>>(lsums, states);
    chunk_output<<<dim3(NCH_, NH_, B_), 256, 0, stream>>>(qbuf, k0buf, v0buf, wgt, states, retr);

    // out = x + retrieved @ w_out^T   (fp32 out, MFMA)
    gemm_mfma<float, 1, 0><<<dim3(D_ / 128, MB / 128), 256, 0, stream>>>(
        retr, wob, nullptr, x, out, nullptr, MB, D_, 512, 6);
}

// Round 4
// 252.620 us; speedup vs baseline: 3.3945x; 1.3411x over previous
//
#include <hip/hip_runtime.h>
#include <hip/hip_bf16.h>

typedef __hip_bfloat16 bf16;
typedef __attribute__((ext_vector_type(8))) short   bf16x8;  // 8 bf16 = 4 VGPRs
typedef __attribute__((ext_vector_type(4))) float   f32x4;

#define B_   4
#define S_   4096
#define D_   768
#define NH_  8
#define DK_  64
#define DV_  64
#define CH_  64              // chunk length
#define NCH_ (S_/CH_)        // 64 chunks
#define DECAY_ 0.95f
#define WSTR_  0.1f

__device__ __forceinline__ float b2f(bf16 v) { return __bfloat162float(v); }
__device__ __forceinline__ bf16  f2b(float v) { return __float2bfloat16(v); }

// async global -> LDS, 16 bytes per lane; lds base must be wave-uniform,
// HW writes lane i at lds + i*16. Global address may be per-lane.
__device__ __forceinline__ void gl2lds16(const bf16* g, bf16* lds) {
    __builtin_amdgcn_global_load_lds(
        (const __attribute__((address_space(1))) void*)g,
        (__attribute__((address_space(3))) void*)lds, 16, 0, 0);
}

// ---------------------------------------------------------------------------
// fp32 -> bf16 cast, 4 elems/thread
// ---------------------------------------------------------------------------
__global__ __launch_bounds__(256) void cast_f2b(const float* __restrict__ src,
                                                bf16* __restrict__ dst, int n) {
    const int i = (blockIdx.x * 256 + threadIdx.x) * 4;
    if (i < n) {
        const float4 v = *reinterpret_cast<const float4*>(src + i);
        union { bf16 b[4]; ushort4 u; } t;
        t.b[0] = f2b(v.x); t.b[1] = f2b(v.y); t.b[2] = f2b(v.z); t.b[3] = f2b(v.w);
        *reinterpret_cast<ushort4*>(dst + i) = t.u;
    }
}

// ---------------------------------------------------------------------------
// MFMA GEMM: C = A @ B^T (+ optional fp32 X add). A: MxK bf16, B: NxK bf16.
// 128x128 tile, BK=32, 256 threads = 4 waves (2x2 of 64x64), 16 MFMA/wave/step.
// KV mode: blocks with blockIdx.x >= nb0 use B1/C1 (k+v fused dispatch).
// ---------------------------------------------------------------------------
template<typename TC, int ADDX, int KV>
__global__ __launch_bounds__(256) void gemm_mfma(const bf16* __restrict__ A,
                                                 const bf16* __restrict__ B0,
                                                 const bf16* __restrict__ B1,
                                                 const float* __restrict__ X,
                                                 TC* __restrict__ C0,
                                                 TC* __restrict__ C1,
                                                 int M, int N, int K, int nb0) {
    __shared__ bf16 As[128 * 32];
    __shared__ bf16 Bs[128 * 32];
    int bx = blockIdx.x;
    const bf16* Bm = B0;
    TC* C = C0;
    if (KV && bx >= nb0) { Bm = B1; C = C1; bx -= nb0; }
    const int bm = blockIdx.y * 128, bn = bx * 128;
    const int tid = threadIdx.x, lane = tid & 63, w = tid >> 6;
    const int quad = lane >> 4, l16 = lane & 15;
    const int wm = (w >> 1) * 64, wn = (w & 1) * 64;

    int ro[2], ko[2];
    #pragma unroll
    for (int c = 0; c < 2; c++) {
        const int o = (w * 2 + c) * 1024 + lane * 16;   // byte offset in tile
        ro[c] = o >> 6;          // tile row (64 B per row of 32 bf16)
        ko[c] = (o & 63) >> 1;   // k element within BK
    }

    f32x4 acc[4][4] = {};

    for (int k0 = 0; k0 < K; k0 += 32) {
        #pragma unroll
        for (int c = 0; c < 2; c++) {
            bf16* lA = &As[(w * 2 + c) * 512];
            bf16* lB = &Bs[(w * 2 + c) * 512];
            gl2lds16(A  + (size_t)(bm + ro[c]) * K + k0 + ko[c], lA);
            gl2lds16(Bm + (size_t)(bn + ro[c]) * K + k0 + ko[c], lB);
        }
        __syncthreads();
        bf16x8 af[4], bfr[4];
        #pragma unroll
        for (int t = 0; t < 4; t++) {
            af[t]  = *reinterpret_cast<const bf16x8*>(&As[(wm + t * 16 + l16) * 32 + quad * 8]);
            bfr[t] = *reinterpret_cast<const bf16x8*>(&Bs[(wn + t * 16 + l16) * 32 + quad * 8]);
        }
        #pragma unroll
        for (int mt = 0; mt < 4; mt++)
            #pragma unroll
            for (int nt = 0; nt < 4; nt++)
                acc[mt][nt] = __builtin_amdgcn_mfma_f32_16x16x32_bf16(
                    af[mt], bfr[nt], acc[mt][nt], 0, 0, 0);
        __syncthreads();
    }

    #pragma unroll
    for (int mt = 0; mt < 4; mt++)
        #pragma unroll
        for (int nt = 0; nt < 4; nt++)
            #pragma unroll
            for (int r = 0; r < 4; r++) {
                const int m = bm + wm + mt * 16 + quad * 4 + r;
                const int n = bn + wn + nt * 16 + l16;
                float v = acc[mt][nt][r];
                if (ADDX) v += X[(size_t)m * N + n];
                if (sizeof(TC) == 2) *(bf16*)&C[(size_t)m * N + n] = f2b(v);
                else                 *(float*)&C[(size_t)m * N + n] = v;
            }
}

// ---------------------------------------------------------------------------
// wgt[s][h] = 0.1 * sigmoid(x0[s,:] . w_gate[h,:])    (batch 0 only)
// ---------------------------------------------------------------------------
__global__ __launch_bounds__(64) void gate_kernel(const float* __restrict__ x,
                                                  const float* __restrict__ wg,
                                                  float* __restrict__ wgt) {
    const int s = blockIdx.x >> 3, h = blockIdx.x & 7;
    const int lane = threadIdx.x;
    const float* xr = x + (size_t)s * D_;
    const float* wr = wg + (size_t)h * D_;
    float sum = 0.f;
    for (int d = lane; d < D_; d += 64) sum += xr[d] * wr[d];
    #pragma unroll
    for (int off = 32; off; off >>= 1) sum += __shfl_down(sum, off);
    if (lane == 0) wgt[s * NH_ + h] = WSTR_ / (1.f + expf(-sum));
}

// ---------------------------------------------------------------------------
// lsumsT[n,h][v*64+k] = sum_{i<CH} 0.95^(CH-1-i) * w_i * v_i[v] * k_i[k]
// (transposed local sums: FW^T accumulation order)
// ---------------------------------------------------------------------------
__global__ __launch_bounds__(256) void chunk_sums(const bf16* __restrict__ k0,
                                                  const bf16* __restrict__ v0,
                                                  const float* __restrict__ wgt,
                                                  float* __restrict__ lsumsT) {
    const int n = blockIdx.x, h = blockIdx.y;
    __shared__ float ks[CH_][65];
    __shared__ float vs[CH_][64];
    __shared__ float cw[CH_];
    const int tid = threadIdx.x;
    for (int e = tid; e < CH_ * 64; e += 256) {
        const int r = e >> 6, c = e & 63;
        const int t = n * CH_ + r;
        ks[r][c] = b2f(k0[(size_t)t * (NH_ * DK_) + h * DK_ + c]);
        vs[r][c] = b2f(v0[(size_t)t * (NH_ * DV_) + h * DV_ + c]);
    }
    if (tid < CH_) {
        const int t = n * CH_ + tid;
        cw[tid] = powf(DECAY_, (float)(CH_ - 1 - tid)) * wgt[t * NH_ + h];
    }
    __syncthreads();
    const int j = tid & 63, ig = tid >> 6;   // j = k-dim, rows = v-dim
    float acc[16] = {};
    for (int idx = 0; idx < CH_; idx++) {
        const float ck = cw[idx] * ks[idx][j];
        #pragma unroll
        for (int r = 0; r < 16; r++) acc[r] += vs[idx][ig * 16 + r] * ck;
    }
    float* out = lsumsT + ((size_t)(n * NH_ + h)) * (DK_ * DV_);
    #pragma unroll
    for (int r = 0; r < 16; r++) out[(ig * 16 + r) * 64 + j] = acc[r];
}

// ---------------------------------------------------------------------------
// statesT[n,h] = FW^T (bf16) before chunk n:  FW_{n+1} = 0.95^CH * FW_n + L_n
// ---------------------------------------------------------------------------
__global__ __launch_bounds__(256) void state_scan(const float* __restrict__ lsumsT,
                                                  bf16* __restrict__ statesT) {
    const int h = blockIdx.x >> 4;
    const int e = (blockIdx.x & 15) * 256 + threadIdx.x;   // 0..4095
    const float dC = powf(DECAY_, (float)CH_);
    float fw = 0.f;
    for (int n = 0; n < NCH_; n++) {
        const size_t idx = ((size_t)(n * NH_ + h)) * (DK_ * DV_) + e;
        statesT[idx] = f2b(fw);
        fw = dC * fw + lsumsT[idx];
    }
}

// ---------------------------------------------------------------------------
// retrieved[t][j] = 0.95^t * (q_t @ FW)[j]
//                 + sum_{s<t} 0.95^(t-1-s)*w_s*(q_t.k_s) * v[s][j]
// MFMA version. grid (NCH_, NH_, B_), 256 threads = 4 waves, each wave owns
// a 16-row m-tile. LDS ~27 KB: Qs/VT aliased, Ks/Am aliased, FWT, tables.
// ---------------------------------------------------------------------------
__global__ __launch_bounds__(256) void chunk_output(const bf16* __restrict__ q,
                                                    const bf16* __restrict__ k0,
                                                    const bf16* __restrict__ v0,
                                                    const float* __restrict__ wgt,
                                                    const bf16* __restrict__ statesT,
                                                    bf16* __restrict__ retr) {
    const int n = blockIdx.x, h = blockIdx.y, b = blockIdx.z;
    __shared__ bf16 QsVT[64 * 72];   // phase A: Qs stride 64; phase B: VT stride 72
    __shared__ bf16 KsAm[64 * 72];   // phase A: Ks stride 64; phase B: Am stride 72
    __shared__ bf16 FWT[64 * 64];    // stride 64
    __shared__ float dpow[64], winv[64];
    const int tid = threadIdx.x, lane = tid & 63, w = tid >> 6;
    const int quad = lane >> 4, l16 = lane & 15;
    const int t0 = n * CH_;

    // --- stage Q, K, FWT via global_load_lds (contiguous stride-64 rows) ---
    #pragma unroll
    for (int c = 0; c < 2; c++) {
        const int seg = w * 2 + c;               // 0..7, covers 8 rows each
        const int row = seg * 8 + (lane >> 3);
        const int col = (lane & 7) * 8;
        gl2lds16(q  + ((size_t)(b * S_ + t0 + row)) * 512 + h * 64 + col, &QsVT[seg * 512]);
        gl2lds16(k0 + ((size_t)(t0 + row)) * 512 + h * 64 + col,          &KsAm[seg * 512]);
        gl2lds16(statesT + ((size_t)(n * NH_ + h)) * 4096 + seg * 512 + lane * 8, &FWT[seg * 512]);
    }
    // --- V tile into registers (transposed write later) ---
    ushort4 vreg[4];
    const int jb = (tid & 15) * 4;   // 4 consecutive v-cols
    const int sb = tid >> 4;         // s = sb + 16*it
    #pragma unroll
    for (int it = 0; it < 4; it++) {
        vreg[it] = *reinterpret_cast<const ushort4*>(
            v0 + ((size_t)(t0 + sb + it * 16)) * 512 + h * 64 + jb);
    }
    if (tid < 64) {
        dpow[tid] = powf(DECAY_, (float)tid);
        winv[tid] = wgt[(t0 + tid) * NH_ + h] * powf(DECAY_, -(float)(tid + 1));
    }
    __syncthreads();

    const int mrow = w * 16;
    float dpow_tt[4], winv_l[4];
    #pragma unroll
    for (int r = 0; r < 4; r++) dpow_tt[r] = dpow[mrow + quad * 4 + r];
    #pragma unroll
    for (int nt = 0; nt < 4; nt++) winv_l[nt] = winv[nt * 16 + l16];

    // --- Phase A: S = Q @ K^T (wave's 16 x 64 slice) ---
    const bf16x8 af0 = *reinterpret_cast<const bf16x8*>(&QsVT[(mrow + l16) * 64 + quad * 8]);
    const bf16x8 af1 = *reinterpret_cast<const bf16x8*>(&QsVT[(mrow + l16) * 64 + 32 + quad * 8]);
    f32x4 acc[4] = {};
    #pragma unroll
    for (int nt = 0; nt < 4; nt++) {
        const bf16x8 b0 = *reinterpret_cast<const bf16x8*>(&KsAm[(nt * 16 + l16) * 64 + quad * 8]);
        const bf16x8 b1 = *reinterpret_cast<const bf16x8*>(&KsAm[(nt * 16 + l16) * 64 + 32 + quad * 8]);
        acc[nt] = __builtin_amdgcn_mfma_f32_16x16x32_bf16(af0, b0, acc[nt], 0, 0, 0);
        acc[nt] = __builtin_amdgcn_mfma_f32_16x16x32_bf16(af1, b1, acc[nt], 0, 0, 0);
    }
    __syncthreads();   // Qs/Ks LDS reads complete; regions can be reused

    // --- mask + decay + gate, write Am (bf16, stride 72) ---
    #pragma unroll
    for (int nt = 0; nt < 4; nt++) {
        const int s = nt * 16 + l16;
        #pragma unroll
        for (int r = 0; r < 4; r++) {
            const int tt = mrow + quad * 4 + r;
            const float v = (s < tt) ? acc[nt][r] * dpow_tt[r] * winv_l[nt] : 0.f;
            KsAm[tt * 72 + s] = f2b(v);
        }
    }
    // --- write V^T (stride 72) from registers ---
    {
        ushort* VT = reinterpret_cast<ushort*>(QsVT);
        #pragma unroll
        for (int it = 0; it < 4; it++) {
            const int s = sb + it * 16;
            VT[(jb + 0) * 72 + s] = vreg[it].x;
            VT[(jb + 1) * 72 + s] = vreg[it].y;
            VT[(jb + 2) * 72 + s] = vreg[it].z;
            VT[(jb + 3) * 72 + s] = vreg[it].w;
        }
    }
    __syncthreads();

    // --- Phase B: O = dpow[t] * (Q @ FWT^T) + Am @ VT^T ---
    f32x4 o[4] = {};
    #pragma unroll
    for (int nt = 0; nt < 4; nt++) {
        const bf16x8 f0 = *reinterpret_cast<const bf16x8*>(&FWT[(nt * 16 + l16) * 64 + quad * 8]);
        const bf16x8 f1 = *reinterpret_cast<const bf16x8*>(&FWT[(nt * 16 + l16) * 64 + 32 + quad * 8]);
        o[nt] = __builtin_amdgcn_mfma_f32_16x16x32_bf16(af0, f0, o[nt], 0, 0, 0);
        o[nt] = __builtin_amdgcn_mfma_f32_16x16x32_bf16(af1, f1, o[nt], 0, 0, 0);
    }
    #pragma unroll
    for (int nt = 0; nt < 4; nt++)
        #pragma unroll
        for (int r = 0; r < 4; r++) o[nt][r] *= dpow_tt[r];

    const bf16x8 a0 = *reinterpret_cast<const bf16x8*>(&KsAm[(mrow + l16) * 72 + quad * 8]);
    const bf16x8 a1 = *reinterpret_cast<const bf16x8*>(&KsAm[(mrow + l16) * 72 + 32 + quad * 8]);
    #pragma unroll
    for (int nt = 0; nt < 4; nt++) {
        const bf16x8 v0f = *reinterpret_cast<const bf16x8*>(&QsVT[(nt * 16 + l16) * 72 + quad * 8]);
        const bf16x8 v1f = *reinterpret_cast<const bf16x8*>(&QsVT[(nt * 16 + l16) * 72 + 32 + quad * 8]);
        o[nt] = __builtin_amdgcn_mfma_f32_16x16x32_bf16(a0, v0f, o[nt], 0, 0, 0);
        o[nt] = __builtin_amdgcn_mfma_f32_16x16x32_bf16(a1, v1f, o[nt], 0, 0, 0);
    }
    #pragma unroll
    for (int nt = 0; nt < 4; nt++)
        #pragma unroll
        for (int r = 0; r < 4; r++) {
            const int tt = mrow + quad * 4 + r;
            retr[((size_t)(b * S_ + t0 + tt)) * 512 + h * 64 + nt * 16 + l16] = f2b(o[nt][r]);
        }
}

// ---------------------------------------------------------------------------
extern "C" void kernel_launch(void* const* d_in, const int* in_sizes, int n_in,
                              void* d_out, int out_size, void* d_ws, size_t ws_size,
                              hipStream_t stream) {
    const float* x  = (const float*)d_in[0];
    const float* wk = (const float*)d_in[1];
    const float* wv = (const float*)d_in[2];
    const float* wq = (const float*)d_in[3];
    const float* wg = (const float*)d_in[4];
    const float* wo = (const float*)d_in[5];
    float* out = (float*)d_out;

    const size_t MB1 = 1ull << 20;
    char* w = (char*)d_ws;
    bf16*  qbuf    = (bf16*)(w);                          // 16 MB
    bf16*  k0buf   = (bf16*)(w + 16 * MB1);               // 4 MB
    bf16*  v0buf   = (bf16*)(w + 20 * MB1);               // 4 MB
    float* wgt     = (float*)(w + 24 * MB1);              // 128 KB
    bf16*  wqb     = (bf16*)(w + 24 * MB1 + (128ull<<10));
    bf16*  wkb     = (bf16*)(w + 24 * MB1 + (128ull<<10) + 1*786432);
    bf16*  wvb     = (bf16*)(w + 24 * MB1 + (128ull<<10) + 2*786432);
    bf16*  wob     = (bf16*)(w + 24 * MB1 + (128ull<<10) + 3*786432);
    char*  base2   = w + 24 * MB1 + (128ull<<10) + 4*786432;   // ~27.125 MB
    bf16*  statesT = (bf16*)(base2);                      // 4 MB
    bf16*  retr    = (bf16*)(base2 + 4 * MB1);            // 16 MB
    float* lsumsT  = (float*)retr;                        // 8 MB, dead before retr
    bf16*  xb      = (bf16*)(base2);                      // 25.2 MB, dead before
                                                          // statesT/retr written

    const int MB = B_ * S_;  // 16384

    // casts (fp32 -> bf16)
    cast_f2b<<<12288, 256, 0, stream>>>(x,  xb,  MB * D_);
    cast_f2b<<<384,   256, 0, stream>>>(wq, wqb, 512 * D_);
    cast_f2b<<<384,   256, 0, stream>>>(wk, wkb, 512 * D_);
    cast_f2b<<<384,   256, 0, stream>>>(wv, wvb, 512 * D_);
    cast_f2b<<<384,   256, 0, stream>>>(wo, wob, D_ * 512);

    gate_kernel<<<S_ * NH_, 64, 0, stream>>>(x, wg, wgt);

    // projections (MFMA)
    gemm_mfma<bf16, 0, 0><<<dim3(512 / 128, MB / 128), 256, 0, stream>>>(
        xb, wqb, nullptr, nullptr, qbuf, nullptr, MB, 512, D_, 4);
    gemm_mfma<bf16, 0, 1><<<dim3(8, S_ / 128), 256, 0, stream>>>(
        xb, wkb, wvb, nullptr, k0buf, v0buf, S_, 512, D_, 4);

    // chunked scan
    chunk_sums<<<dim3(NCH_, NH_), 256, 0, stream>>>(k0buf, v0buf, wgt, lsumsT);
    state_scan<<<NH_ * 16, 256, 0, stream>>>(lsumsT, statesT);
    chunk_output<<<dim3(NCH_, NH_, B_), 256, 0, stream>>>(qbuf, k0buf, v0buf, wgt, statesT, retr);

    // out = x + retrieved @ w_out^T   (fp32 out, MFMA)
    gemm_mfma<float, 1, 0><<<dim3(D_ / 128, MB / 128), 256, 0, stream>>>(
        retr, wob, nullptr, x, out, nullptr, MB, D_, 512, 6);
}

// Round 5
// 224.078 us; speedup vs baseline: 3.8269x; 1.1274x over previous
//
#include <hip/hip_runtime.h>
#include <hip/hip_bf16.h>

typedef __hip_bfloat16 bf16;
typedef __attribute__((ext_vector_type(8))) short   bf16x8;  // 8 bf16 = 4 VGPRs
typedef __attribute__((ext_vector_type(4))) float   f32x4;

#define B_   4
#define S_   4096
#define D_   768
#define NH_  8
#define DK_  64
#define DV_  64
#define CH_  64              // chunk length
#define NCH_ (S_/CH_)        // 64 chunks
#define DECAY_ 0.95f
#define WSTR_  0.1f

__device__ __forceinline__ float b2f(bf16 v) { return __bfloat162float(v); }
__device__ __forceinline__ bf16  f2b(float v) { return __float2bfloat16(v); }

// async global -> LDS, 16 bytes per lane; lds base must be wave-uniform,
// HW writes lane i at lds + i*16.
__device__ __forceinline__ void gl2lds16(const bf16* g, bf16* lds) {
    __builtin_amdgcn_global_load_lds(
        (const __attribute__((address_space(1))) void*)g,
        (__attribute__((address_space(3))) void*)lds, 16, 0, 0);
}

// ---------------------------------------------------------------------------
// Fused x cast (fp32->bf16) + gate: one block per row s of x (16384 rows).
// Batch-0 rows additionally compute wgt[s][h] = 0.1*sigmoid(x[s].wg[h]).
// 192 threads = 3 waves; each thread owns 4 consecutive fp32.
// ---------------------------------------------------------------------------
__global__ __launch_bounds__(192) void cast_gate(const float* __restrict__ x,
                                                 bf16* __restrict__ xb,
                                                 const float* __restrict__ wg,
                                                 float* __restrict__ wgt) {
    const int s = blockIdx.x;
    const int tid = threadIdx.x;
    const float4 v = *reinterpret_cast<const float4*>(x + (size_t)s * D_ + tid * 4);
    union { bf16 b4[4]; ushort4 u; } t;
    t.b4[0] = f2b(v.x); t.b4[1] = f2b(v.y); t.b4[2] = f2b(v.z); t.b4[3] = f2b(v.w);
    *reinterpret_cast<ushort4*>(xb + (size_t)s * D_ + tid * 4) = t.u;

    if (s < S_) {   // batch 0 only
        __shared__ float red[3 * 8];
        float p[8];
        const float* wgp = wg + tid * 4;
        #pragma unroll
        for (int h = 0; h < 8; h++) {
            const float4 wv = *reinterpret_cast<const float4*>(wgp + h * D_);
            p[h] = v.x * wv.x + v.y * wv.y + v.z * wv.z + v.w * wv.w;
        }
        #pragma unroll
        for (int h = 0; h < 8; h++)
            #pragma unroll
            for (int off = 32; off; off >>= 1) p[h] += __shfl_down(p[h], off);
        const int w = tid >> 6, lane = tid & 63;
        if (lane == 0) {
            #pragma unroll
            for (int h = 0; h < 8; h++) red[w * 8 + h] = p[h];
        }
        __syncthreads();
        if (tid < 8) {
            const float sum = red[tid] + red[8 + tid] + red[16 + tid];
            wgt[s * NH_ + tid] = WSTR_ / (1.f + expf(-sum));
        }
    }
}

// ---------------------------------------------------------------------------
// All four weight matrices cast in one dispatch (393216 elems each).
// ---------------------------------------------------------------------------
__global__ __launch_bounds__(256) void cast_w4(const float* __restrict__ wq,
                                               const float* __restrict__ wk,
                                               const float* __restrict__ wv,
                                               const float* __restrict__ wo,
                                               bf16* __restrict__ dq, bf16* __restrict__ dk,
                                               bf16* __restrict__ dv, bf16* __restrict__ dob) {
    const int which = blockIdx.x / 384, b = blockIdx.x % 384;
    const float* src = which == 0 ? wq : which == 1 ? wk : which == 2 ? wv : wo;
    bf16*       dst = which == 0 ? dq : which == 1 ? dk : which == 2 ? dv : dob;
    const int i = (b * 256 + threadIdx.x) * 4;
    const float4 v = *reinterpret_cast<const float4*>(src + i);
    union { bf16 b4[4]; ushort4 u; } t;
    t.b4[0] = f2b(v.x); t.b4[1] = f2b(v.y); t.b4[2] = f2b(v.z); t.b4[3] = f2b(v.w);
    *reinterpret_cast<ushort4*>(dst + i) = t.u;
}

// ---------------------------------------------------------------------------
// MFMA GEMM: C = A @ B^T (+ optional fp32 X add). A: MxK bf16, B: NxK bf16.
// 128x128 tile, BK=32, 256 threads = 4 waves (2x2 of 64x64), 16 MFMA/wave/step.
// XCD swizzle: blocks sharing by land on one XCD so the A-strip stays in its L2.
// KV mode: blocks with bx >= nb0 use B1/C1 (k+v fused dispatch).
// ---------------------------------------------------------------------------
template<typename TC, int ADDX, int KV>
__global__ __launch_bounds__(256) void gemm_mfma(const bf16* __restrict__ A,
                                                 const bf16* __restrict__ B0,
                                                 const bf16* __restrict__ B1,
                                                 const float* __restrict__ X,
                                                 TC* __restrict__ C0,
                                                 TC* __restrict__ C1,
                                                 int M, int N, int K, int nb0) {
    __shared__ bf16 As[128 * 32];
    __shared__ bf16 Bs[128 * 32];
    // XCD-aware remap (gy must be divisible by 8; all our grids are)
    int bx, by;
    {
        const int gx = gridDim.x, gy = gridDim.y;
        const int L = blockIdx.y * gx + blockIdx.x;
        if ((gy & 7) == 0) {
            const int rpx = gy >> 3;
            const int xcd = L & 7;
            const int i   = L >> 3;
            by = xcd * rpx + i / gx;
            bx = i % gx;
        } else { bx = blockIdx.x; by = blockIdx.y; }
    }
    const bf16* Bm = B0;
    TC* C = C0;
    if (KV && bx >= nb0) { Bm = B1; C = C1; bx -= nb0; }
    const int bm = by * 128, bn = bx * 128;
    const int tid = threadIdx.x, lane = tid & 63, w = tid >> 6;
    const int quad = lane >> 4, l16 = lane & 15;
    const int wm = (w >> 1) * 64, wn = (w & 1) * 64;

    int ro[2], ko[2];
    #pragma unroll
    for (int c = 0; c < 2; c++) {
        const int o = (w * 2 + c) * 1024 + lane * 16;   // byte offset in tile
        ro[c] = o >> 6;          // tile row (64 B per row of 32 bf16)
        ko[c] = (o & 63) >> 1;   // k element within BK
    }

    f32x4 acc[4][4] = {};

    for (int k0 = 0; k0 < K; k0 += 32) {
        #pragma unroll
        for (int c = 0; c < 2; c++) {
            bf16* lA = &As[(w * 2 + c) * 512];
            bf16* lB = &Bs[(w * 2 + c) * 512];
            gl2lds16(A  + (size_t)(bm + ro[c]) * K + k0 + ko[c], lA);
            gl2lds16(Bm + (size_t)(bn + ro[c]) * K + k0 + ko[c], lB);
        }
        __syncthreads();
        bf16x8 af[4], bfr[4];
        #pragma unroll
        for (int t = 0; t < 4; t++) {
            af[t]  = *reinterpret_cast<const bf16x8*>(&As[(wm + t * 16 + l16) * 32 + quad * 8]);
            bfr[t] = *reinterpret_cast<const bf16x8*>(&Bs[(wn + t * 16 + l16) * 32 + quad * 8]);
        }
        #pragma unroll
        for (int mt = 0; mt < 4; mt++)
            #pragma unroll
            for (int nt = 0; nt < 4; nt++)
                acc[mt][nt] = __builtin_amdgcn_mfma_f32_16x16x32_bf16(
                    af[mt], bfr[nt], acc[mt][nt], 0, 0, 0);
        __syncthreads();
    }

    #pragma unroll
    for (int mt = 0; mt < 4; mt++)
        #pragma unroll
        for (int nt = 0; nt < 4; nt++)
            #pragma unroll
            for (int r = 0; r < 4; r++) {
                const int m = bm + wm + mt * 16 + quad * 4 + r;
                const int n = bn + wn + nt * 16 + l16;
                float v = acc[mt][nt][r];
                if (ADDX) v += X[(size_t)m * N + n];
                if (sizeof(TC) == 2) *(bf16*)&C[(size_t)m * N + n] = f2b(v);
                else                 *(float*)&C[(size_t)m * N + n] = v;
            }
}

// ---------------------------------------------------------------------------
// lsumsT[n,h][v*64+k] = sum_{i<CH} 0.95^(CH-1-i) * w_i * v_i[v] * k_i[k]
// (transposed local sums, bf16 out)
// ---------------------------------------------------------------------------
__global__ __launch_bounds__(256) void chunk_sums(const bf16* __restrict__ k0,
                                                  const bf16* __restrict__ v0,
                                                  const float* __restrict__ wgt,
                                                  bf16* __restrict__ lsumsT) {
    const int n = blockIdx.x, h = blockIdx.y;
    __shared__ float ks[CH_][65];
    __shared__ float vs[CH_][64];
    __shared__ float cw[CH_];
    const int tid = threadIdx.x;
    for (int e = tid; e < CH_ * 64; e += 256) {
        const int r = e >> 6, c = e & 63;
        const int t = n * CH_ + r;
        ks[r][c] = b2f(k0[(size_t)t * (NH_ * DK_) + h * DK_ + c]);
        vs[r][c] = b2f(v0[(size_t)t * (NH_ * DV_) + h * DV_ + c]);
    }
    if (tid < CH_) {
        const int t = n * CH_ + tid;
        cw[tid] = powf(DECAY_, (float)(CH_ - 1 - tid)) * wgt[t * NH_ + h];
    }
    __syncthreads();
    const int j = tid & 63, ig = tid >> 6;   // j = k-dim, rows = v-dim
    float acc[16] = {};
    for (int idx = 0; idx < CH_; idx++) {
        const float ck = cw[idx] * ks[idx][j];
        #pragma unroll
        for (int r = 0; r < 16; r++) acc[r] += vs[idx][ig * 16 + r] * ck;
    }
    bf16* out = lsumsT + ((size_t)(n * NH_ + h)) * (DK_ * DV_);
    #pragma unroll
    for (int r = 0; r < 16; r++) out[(ig * 16 + r) * 64 + j] = f2b(acc[r]);
}

// ---------------------------------------------------------------------------
// statesT[n,h] = FW^T (bf16) before chunk n:  FW_{n+1} = 0.95^CH * FW_n + L_n
// ---------------------------------------------------------------------------
__global__ __launch_bounds__(256) void state_scan(const bf16* __restrict__ lsumsT,
                                                  bf16* __restrict__ statesT) {
    const int h = blockIdx.x >> 4;
    const int e = (blockIdx.x & 15) * 256 + threadIdx.x;   // 0..4095
    const float dC = powf(DECAY_, (float)CH_);
    float fw = 0.f;
    for (int n = 0; n < NCH_; n++) {
        const size_t idx = ((size_t)(n * NH_ + h)) * (DK_ * DV_) + e;
        statesT[idx] = f2b(fw);
        fw = dC * fw + b2f(lsumsT[idx]);
    }
}

// ---------------------------------------------------------------------------
// retrieved[t][j] = 0.95^t * (q_t @ FW)[j]
//                 + sum_{s<t} 0.95^(t-1-s)*w_s*(q_t.k_s) * v[s][j]
// MFMA. grid (NCH_, NH_, B_), 256 threads = 4 waves, 16-row m-tile per wave.
// ---------------------------------------------------------------------------
__global__ __launch_bounds__(256) void chunk_output(const bf16* __restrict__ q,
                                                    const bf16* __restrict__ k0,
                                                    const bf16* __restrict__ v0,
                                                    const float* __restrict__ wgt,
                                                    const bf16* __restrict__ statesT,
                                                    bf16* __restrict__ retr) {
    const int n = blockIdx.x, h = blockIdx.y, b = blockIdx.z;
    __shared__ bf16 QsVT[64 * 72];   // phase A: Qs stride 64; phase B: VT stride 72
    __shared__ bf16 KsAm[64 * 72];   // phase A: Ks stride 64; phase B: Am stride 72
    __shared__ bf16 FWT[64 * 64];    // stride 64
    __shared__ float dpow[64], winv[64];
    const int tid = threadIdx.x, lane = tid & 63, w = tid >> 6;
    const int quad = lane >> 4, l16 = lane & 15;
    const int t0 = n * CH_;

    #pragma unroll
    for (int c = 0; c < 2; c++) {
        const int seg = w * 2 + c;               // 0..7, covers 8 rows each
        const int row = seg * 8 + (lane >> 3);
        const int col = (lane & 7) * 8;
        gl2lds16(q  + ((size_t)(b * S_ + t0 + row)) * 512 + h * 64 + col, &QsVT[seg * 512]);
        gl2lds16(k0 + ((size_t)(t0 + row)) * 512 + h * 64 + col,          &KsAm[seg * 512]);
        gl2lds16(statesT + ((size_t)(n * NH_ + h)) * 4096 + seg * 512 + lane * 8, &FWT[seg * 512]);
    }
    ushort4 vreg[4];
    const int jb = (tid & 15) * 4;   // 4 consecutive v-cols
    const int sb = tid >> 4;         // s = sb + 16*it
    #pragma unroll
    for (int it = 0; it < 4; it++) {
        vreg[it] = *reinterpret_cast<const ushort4*>(
            v0 + ((size_t)(t0 + sb + it * 16)) * 512 + h * 64 + jb);
    }
    if (tid < 64) {
        dpow[tid] = powf(DECAY_, (float)tid);
        winv[tid] = wgt[(t0 + tid) * NH_ + h] * powf(DECAY_, -(float)(tid + 1));
    }
    __syncthreads();

    const int mrow = w * 16;
    float dpow_tt[4], winv_l[4];
    #pragma unroll
    for (int r = 0; r < 4; r++) dpow_tt[r] = dpow[mrow + quad * 4 + r];
    #pragma unroll
    for (int nt = 0; nt < 4; nt++) winv_l[nt] = winv[nt * 16 + l16];

    // Phase A: S = Q @ K^T (wave's 16 x 64 slice)
    const bf16x8 af0 = *reinterpret_cast<const bf16x8*>(&QsVT[(mrow + l16) * 64 + quad * 8]);
    const bf16x8 af1 = *reinterpret_cast<const bf16x8*>(&QsVT[(mrow + l16) * 64 + 32 + quad * 8]);
    f32x4 acc[4] = {};
    #pragma unroll
    for (int nt = 0; nt < 4; nt++) {
        const bf16x8 b0 = *reinterpret_cast<const bf16x8*>(&KsAm[(nt * 16 + l16) * 64 + quad * 8]);
        const bf16x8 b1 = *reinterpret_cast<const bf16x8*>(&KsAm[(nt * 16 + l16) * 64 + 32 + quad * 8]);
        acc[nt] = __builtin_amdgcn_mfma_f32_16x16x32_bf16(af0, b0, acc[nt], 0, 0, 0);
        acc[nt] = __builtin_amdgcn_mfma_f32_16x16x32_bf16(af1, b1, acc[nt], 0, 0, 0);
    }
    __syncthreads();

    // mask + decay + gate, write Am (bf16, stride 72)
    #pragma unroll
    for (int nt = 0; nt < 4; nt++) {
        const int s = nt * 16 + l16;
        #pragma unroll
        for (int r = 0; r < 4; r++) {
            const int tt = mrow + quad * 4 + r;
            const float v = (s < tt) ? acc[nt][r] * dpow_tt[r] * winv_l[nt] : 0.f;
            KsAm[tt * 72 + s] = f2b(v);
        }
    }
    // write V^T (stride 72) from registers
    {
        ushort* VT = reinterpret_cast<ushort*>(QsVT);
        #pragma unroll
        for (int it = 0; it < 4; it++) {
            const int s = sb + it * 16;
            VT[(jb + 0) * 72 + s] = vreg[it].x;
            VT[(jb + 1) * 72 + s] = vreg[it].y;
            VT[(jb + 2) * 72 + s] = vreg[it].z;
            VT[(jb + 3) * 72 + s] = vreg[it].w;
        }
    }
    __syncthreads();

    // Phase B: O = dpow[t] * (Q @ FWT^T) + Am @ VT^T
    f32x4 o[4] = {};
    #pragma unroll
    for (int nt = 0; nt < 4; nt++) {
        const bf16x8 f0 = *reinterpret_cast<const bf16x8*>(&FWT[(nt * 16 + l16) * 64 + quad * 8]);
        const bf16x8 f1 = *reinterpret_cast<const bf16x8*>(&FWT[(nt * 16 + l16) * 64 + 32 + quad * 8]);
        o[nt] = __builtin_amdgcn_mfma_f32_16x16x32_bf16(af0, f0, o[nt], 0, 0, 0);
        o[nt] = __builtin_amdgcn_mfma_f32_16x16x32_bf16(af1, f1, o[nt], 0, 0, 0);
    }
    #pragma unroll
    for (int nt = 0; nt < 4; nt++)
        #pragma unroll
        for (int r = 0; r < 4; r++) o[nt][r] *= dpow_tt[r];

    const bf16x8 a0 = *reinterpret_cast<const bf16x8*>(&KsAm[(mrow + l16) * 72 + quad * 8]);
    const bf16x8 a1 = *reinterpret_cast<const bf16x8*>(&KsAm[(mrow + l16) * 72 + 32 + quad * 8]);
    #pragma unroll
    for (int nt = 0; nt < 4; nt++) {
        const bf16x8 v0f = *reinterpret_cast<const bf16x8*>(&QsVT[(nt * 16 + l16) * 72 + quad * 8]);
        const bf16x8 v1f = *reinterpret_cast<const bf16x8*>(&QsVT[(nt * 16 + l16) * 72 + 32 + quad * 8]);
        o[nt] = __builtin_amdgcn_mfma_f32_16x16x32_bf16(a0, v0f, o[nt], 0, 0, 0);
        o[nt] = __builtin_amdgcn_mfma_f32_16x16x32_bf16(a1, v1f, o[nt], 0, 0, 0);
    }
    #pragma unroll
    for (int nt = 0; nt < 4; nt++)
        #pragma unroll
        for (int r = 0; r < 4; r++) {
            const int tt = mrow + quad * 4 + r;
            retr[((size_t)(b * S_ + t0 + tt)) * 512 + h * 64 + nt * 16 + l16] = f2b(o[nt][r]);
        }
}

// ---------------------------------------------------------------------------
extern "C" void kernel_launch(void* const* d_in, const int* in_sizes, int n_in,
                              void* d_out, int out_size, void* d_ws, size_t ws_size,
                              hipStream_t stream) {
    const float* x  = (const float*)d_in[0];
    const float* wk = (const float*)d_in[1];
    const float* wv = (const float*)d_in[2];
    const float* wq = (const float*)d_in[3];
    const float* wg = (const float*)d_in[4];
    const float* wo = (const float*)d_in[5];
    float* out = (float*)d_out;

    const size_t MB1 = 1ull << 20;
    char* w = (char*)d_ws;
    bf16*  qbuf    = (bf16*)(w);                          // 16 MB
    bf16*  k0buf   = (bf16*)(w + 16 * MB1);               // 4 MB
    bf16*  v0buf   = (bf16*)(w + 20 * MB1);               // 4 MB
    float* wgt     = (float*)(w + 24 * MB1);              // 128 KB
    bf16*  wqb     = (bf16*)(w + 24 * MB1 + (128ull<<10));
    bf16*  wkb     = (bf16*)(w + 24 * MB1 + (128ull<<10) + 1*786432);
    bf16*  wvb     = (bf16*)(w + 24 * MB1 + (128ull<<10) + 2*786432);
    bf16*  wob     = (bf16*)(w + 24 * MB1 + (128ull<<10) + 3*786432);
    char*  base2   = w + 24 * MB1 + (128ull<<10) + 4*786432;   // ~27.125 MB
    bf16*  statesT = (bf16*)(base2);                      // 4 MB
    bf16*  retr    = (bf16*)(base2 + 4 * MB1);            // 16 MB
    bf16*  lsumsT  = retr;                                // 4 MB, dead before retr
    bf16*  xb      = (bf16*)(base2);                      // 25.2 MB; dead before
                                                          // statesT/lsumsT written

    const int MB = B_ * S_;  // 16384

    // fused cast(x) + gate; merged weight casts
    cast_gate<<<MB, 192, 0, stream>>>(x, xb, wg, wgt);
    cast_w4<<<1536, 256, 0, stream>>>(wq, wk, wv, wo, wqb, wkb, wvb, wob);

    // projections (MFMA, XCD-swizzled)
    gemm_mfma<bf16, 0, 0><<<dim3(512 / 128, MB / 128), 256, 0, stream>>>(
        xb, wqb, nullptr, nullptr, qbuf, nullptr, MB, 512, D_, 4);
    gemm_mfma<bf16, 0, 1><<<dim3(8, S_ / 128), 256, 0, stream>>>(
        xb, wkb, wvb, nullptr, k0buf, v0buf, S_, 512, D_, 4);

    // chunked scan
    chunk_sums<<<dim3(NCH_, NH_), 256, 0, stream>>>(k0buf, v0buf, wgt, lsumsT);
    state_scan<<<NH_ * 16, 256, 0, stream>>>(lsumsT, statesT);
    chunk_output<<<dim3(NCH_, NH_, B_), 256, 0, stream>>>(qbuf, k0buf, v0buf, wgt, statesT, retr);

    // out = x + retrieved @ w_out^T   (fp32 out, MFMA, XCD-swizzled)
    gemm_mfma<float, 1, 0><<<dim3(D_ / 128, MB / 128), 256, 0, stream>>>(
        retr, wob, nullptr, x, out, nullptr, MB, D_, 512, 6);
}

// Round 6
// 200.310 us; speedup vs baseline: 4.2810x; 1.1187x over previous
//
#include <hip/hip_runtime.h>
#include <hip/hip_bf16.h>

typedef __hip_bfloat16 bf16;
typedef __attribute__((ext_vector_type(8))) short   bf16x8;  // 8 bf16 = 4 VGPRs
typedef __attribute__((ext_vector_type(4))) float   f32x4;

#define B_   4
#define S_   4096
#define D_   768
#define NH_  8
#define DK_  64
#define DV_  64
#define CH_  64              // chunk length
#define NCH_ (S_/CH_)        // 64 chunks
#define DECAY_ 0.95f
#define WSTR_  0.1f

__device__ __forceinline__ float b2f(bf16 v) { return __bfloat162float(v); }
__device__ __forceinline__ bf16  f2b(float v) { return __float2bfloat16(v); }

// async global -> LDS, 16 bytes per lane; lds base must be wave-uniform,
// HW writes lane i at lds + i*16.
__device__ __forceinline__ void gl2lds16(const bf16* g, bf16* lds) {
    __builtin_amdgcn_global_load_lds(
        (const __attribute__((address_space(1))) void*)g,
        (__attribute__((address_space(3))) void*)lds, 16, 0, 0);
}

// ---------------------------------------------------------------------------
// Fused cast kernel, 192 threads:
//  blocks [0, 16384): x row cast fp32->bf16; rows < 4096 also compute gate.
//  blocks [16384, 18432): the four 512x768 weight matrices cast (512 blk each).
// ---------------------------------------------------------------------------
__global__ __launch_bounds__(192) void cast_fused(const float* __restrict__ x,
                                                  bf16* __restrict__ xb,
                                                  const float* __restrict__ wg,
                                                  float* __restrict__ wgt,
                                                  const float* __restrict__ wq,
                                                  const float* __restrict__ wk,
                                                  const float* __restrict__ wv,
                                                  const float* __restrict__ wo,
                                                  bf16* __restrict__ dq, bf16* __restrict__ dk,
                                                  bf16* __restrict__ dv, bf16* __restrict__ dob) {
    const int tid = threadIdx.x;
    if (blockIdx.x >= (B_ * S_)) {
        const int idx = blockIdx.x - B_ * S_;          // 0..2047
        const int which = idx >> 9, b = idx & 511;     // 512 blocks per matrix
        const float* src = which == 0 ? wq : which == 1 ? wk : which == 2 ? wv : wo;
        bf16*       dst = which == 0 ? dq : which == 1 ? dk : which == 2 ? dv : dob;
        const int i = (b * 192 + tid) * 4;
        const float4 v = *reinterpret_cast<const float4*>(src + i);
        union { bf16 b4[4]; ushort4 u; } t;
        t.b4[0] = f2b(v.x); t.b4[1] = f2b(v.y); t.b4[2] = f2b(v.z); t.b4[3] = f2b(v.w);
        *reinterpret_cast<ushort4*>(dst + i) = t.u;
        return;
    }
    const int s = blockIdx.x;
    const float4 v = *reinterpret_cast<const float4*>(x + (size_t)s * D_ + tid * 4);
    union { bf16 b4[4]; ushort4 u; } t;
    t.b4[0] = f2b(v.x); t.b4[1] = f2b(v.y); t.b4[2] = f2b(v.z); t.b4[3] = f2b(v.w);
    *reinterpret_cast<ushort4*>(xb + (size_t)s * D_ + tid * 4) = t.u;

    if (s < S_) {   // batch 0 only
        __shared__ float red[3 * 8];
        float p[8];
        const float* wgp = wg + tid * 4;
        #pragma unroll
        for (int h = 0; h < 8; h++) {
            const float4 wv4 = *reinterpret_cast<const float4*>(wgp + h * D_);
            p[h] = v.x * wv4.x + v.y * wv4.y + v.z * wv4.z + v.w * wv4.w;
        }
        #pragma unroll
        for (int h = 0; h < 8; h++)
            #pragma unroll
            for (int off = 32; off; off >>= 1) p[h] += __shfl_down(p[h], off);
        const int w = tid >> 6, lane = tid & 63;
        if (lane == 0) {
            #pragma unroll
            for (int h = 0; h < 8; h++) red[w * 8 + h] = p[h];
        }
        __syncthreads();
        if (tid < 8) {
            const float sum = red[tid] + red[8 + tid] + red[16 + tid];
            wgt[s * NH_ + tid] = WSTR_ / (1.f + expf(-sum));
        }
    }
}

// ---------------------------------------------------------------------------
// Shared MFMA GEMM body: C = A @ B^T (+X), 128x128 tile, BK=64, 4 waves.
// LDS layout XOR-swizzled: colblock p = cb ^ (row&7) kills bank conflicts;
// staging lanes fetch the XOR'd global column (LDS dest stays contiguous).
// ---------------------------------------------------------------------------
template<typename TC, int ADDX, int NITER>
__device__ __forceinline__ void gemm_body(bf16* As, bf16* Bs,
                                          const bf16* __restrict__ A,
                                          const bf16* __restrict__ Bm,
                                          const float* __restrict__ X,
                                          TC* __restrict__ C,
                                          int bm, int bn, int K, int N) {
    const int tid = threadIdx.x, lane = tid & 63, w = tid >> 6;
    const int quad = lane >> 4, l16 = lane & 15;
    const int wm = (w >> 1) * 64, wn = (w & 1) * 64;
    const int lrow = lane >> 3;                         // 0..7 within segment
    const int lcol = ((lane & 7) ^ lrow) * 8;           // XOR-swizzled source col

    f32x4 acc[4][4] = {};

    for (int it = 0; it < NITER; it++) {
        const int k0 = it * 64;
        #pragma unroll
        for (int c = 0; c < 4; c++) {
            const int seg = w * 4 + c;                  // 0..15, 8 rows each
            const int row = seg * 8 + lrow;
            gl2lds16(A  + (size_t)(bm + row) * K + k0 + lcol, &As[seg * 512]);
            gl2lds16(Bm + (size_t)(bn + row) * K + k0 + lcol, &Bs[seg * 512]);
        }
        __syncthreads();
        #pragma unroll
        for (int kh = 0; kh < 2; kh++) {
            bf16x8 af[4], bfr[4];
            #pragma unroll
            for (int t = 0; t < 4; t++) {
                const int cb = ((kh * 4 + quad) ^ (l16 & 7)) * 8;
                af[t]  = *reinterpret_cast<const bf16x8*>(&As[(wm + t * 16 + l16) * 64 + cb]);
                bfr[t] = *reinterpret_cast<const bf16x8*>(&Bs[(wn + t * 16 + l16) * 64 + cb]);
            }
            #pragma unroll
            for (int mt = 0; mt < 4; mt++)
                #pragma unroll
                for (int nt = 0; nt < 4; nt++)
                    acc[mt][nt] = __builtin_amdgcn_mfma_f32_16x16x32_bf16(
                        af[mt], bfr[nt], acc[mt][nt], 0, 0, 0);
        }
        __syncthreads();
    }

    #pragma unroll
    for (int mt = 0; mt < 4; mt++)
        #pragma unroll
        for (int nt = 0; nt < 4; nt++)
            #pragma unroll
            for (int r = 0; r < 4; r++) {
                const int m = bm + wm + mt * 16 + quad * 4 + r;
                const int n = bn + wn + nt * 16 + l16;
                float v = acc[mt][nt][r];
                if (ADDX) v += X[(size_t)m * N + n];
                if (sizeof(TC) == 2) *(bf16*)&C[(size_t)m * N + n] = f2b(v);
                else                 *(float*)&C[(size_t)m * N + n] = v;
            }
}

// ---------------------------------------------------------------------------
// Fused q/k/v projection: 768 blocks, K=768, N=512 for all.
//  per XCD k (=id&7, j=id>>3): j<64 -> q (strip k+8*(j>>2), ntile j&3)
//                              j>=64 -> kv (strip k+8*((j-64)>>3), b8=(j-64)&7)
//  q strips cover all 16384 rows; kv strips rows 0..4095 (co-located with q).
// ---------------------------------------------------------------------------
__global__ __launch_bounds__(256) void proj_fused(const bf16* __restrict__ xb,
                                                  const bf16* __restrict__ wqb,
                                                  const bf16* __restrict__ wkb,
                                                  const bf16* __restrict__ wvb,
                                                  bf16* __restrict__ qbuf,
                                                  bf16* __restrict__ k0buf,
                                                  bf16* __restrict__ v0buf) {
    __shared__ bf16 As[128 * 64];
    __shared__ bf16 Bs[128 * 64];
    const int id = blockIdx.x;
    const int xcd = id & 7;
    int j = id >> 3;                                    // 0..95
    const bf16* Bm; bf16* C; int bm, bn;
    if (j < 64) {
        bm = (xcd + ((j >> 2) << 3)) * 128;             // q strip
        bn = (j & 3) * 128;
        Bm = wqb; C = qbuf;
    } else {
        j -= 64;
        bm = (xcd + ((j >> 3) << 3)) * 128;             // kv strip (rows < 4096)
        const int b8 = j & 7;
        bn = (b8 & 3) * 128;
        Bm = (b8 < 4) ? wkb : wvb;
        C  = (b8 < 4) ? k0buf : v0buf;
    }
    gemm_body<bf16, 0, 12>(As, Bs, xb, Bm, nullptr, C, bm, bn, D_, 512);
}

// ---------------------------------------------------------------------------
// Out-projection: out = x + retr @ wo^T.  grid (6,128), K=512, N=768.
// ---------------------------------------------------------------------------
__global__ __launch_bounds__(256) void gemm_out(const bf16* __restrict__ retr,
                                                const bf16* __restrict__ wob,
                                                const float* __restrict__ x,
                                                float* __restrict__ out) {
    __shared__ bf16 As[128 * 64];
    __shared__ bf16 Bs[128 * 64];
    // XCD swizzle: blocks sharing an A-strip (by) land on one XCD.
    const int gx = gridDim.x, gy = gridDim.y;
    const int L = blockIdx.y * gx + blockIdx.x;
    const int rpx = gy >> 3;
    const int xcd = L & 7;
    const int i   = L >> 3;
    const int by = xcd * rpx + i / gx;
    const int bx = i % gx;
    gemm_body<float, 1, 8>(As, Bs, retr, wob, x, out, by * 128, bx * 128, 512, D_);
}

// ---------------------------------------------------------------------------
// lsumsT[n,h][v*64+k] = sum_{i<CH} 0.95^(CH-1-i) * w_i * v_i[v] * k_i[k]
// ---------------------------------------------------------------------------
__global__ __launch_bounds__(256) void chunk_sums(const bf16* __restrict__ k0,
                                                  const bf16* __restrict__ v0,
                                                  const float* __restrict__ wgt,
                                                  bf16* __restrict__ lsumsT) {
    const int n = blockIdx.x, h = blockIdx.y;
    __shared__ float ks[CH_][65];
    __shared__ float vs[CH_][64];
    __shared__ float cw[CH_];
    const int tid = threadIdx.x;
    for (int e = tid; e < CH_ * 64; e += 256) {
        const int r = e >> 6, c = e & 63;
        const int t = n * CH_ + r;
        ks[r][c] = b2f(k0[(size_t)t * (NH_ * DK_) + h * DK_ + c]);
        vs[r][c] = b2f(v0[(size_t)t * (NH_ * DV_) + h * DV_ + c]);
    }
    if (tid < CH_) {
        const int t = n * CH_ + tid;
        cw[tid] = powf(DECAY_, (float)(CH_ - 1 - tid)) * wgt[t * NH_ + h];
    }
    __syncthreads();
    const int j = tid & 63, ig = tid >> 6;   // j = k-dim, rows = v-dim
    float acc[16] = {};
    for (int idx = 0; idx < CH_; idx++) {
        const float ck = cw[idx] * ks[idx][j];
        #pragma unroll
        for (int r = 0; r < 16; r++) acc[r] += vs[idx][ig * 16 + r] * ck;
    }
    bf16* outp = lsumsT + ((size_t)(n * NH_ + h)) * (DK_ * DV_);
    #pragma unroll
    for (int r = 0; r < 16; r++) outp[(ig * 16 + r) * 64 + j] = f2b(acc[r]);
}

__device__ __forceinline__ void cvt4(ushort4 u, float f[4]) {
    union { unsigned u; float f; } c;
    c.u = (unsigned)u.x << 16; f[0] = c.f;
    c.u = (unsigned)u.y << 16; f[1] = c.f;
    c.u = (unsigned)u.z << 16; f[2] = c.f;
    c.u = (unsigned)u.w << 16; f[3] = c.f;
}

// ---------------------------------------------------------------------------
// chunk_output with fused state combine:
//   FW^T(n) = sum_{j=1..4} dC^{j-1} * L[n-j]   (dC = 0.95^64 = 0.0375;
//   term 5 ~ 2e-6 relative -- far below bf16 noise, so 4 terms suffice)
// then  retrieved[t][j] = 0.95^t*(q_t @ FW)[j] + sum_{s<t} A[t,s]*v[s][j].
// Qs/Ks/FWT use the XOR-swizzled 64-stride layout (bank-conflict-free);
// Am/VT use stride 72 (naturally spread).
// ---------------------------------------------------------------------------
__global__ __launch_bounds__(256) void chunk_output(const bf16* __restrict__ q,
                                                    const bf16* __restrict__ k0,
                                                    const bf16* __restrict__ v0,
                                                    const float* __restrict__ wgt,
                                                    const bf16* __restrict__ lsumsT,
                                                    bf16* __restrict__ retr) {
    const int n = blockIdx.x, h = blockIdx.y, b = blockIdx.z;
    __shared__ bf16 QsVT[64 * 72];   // phase A: Qs (sw64); phase B: VT stride 72
    __shared__ bf16 KsAm[64 * 72];   // phase A: Ks (sw64); phase B: Am stride 72
    __shared__ bf16 FWT[64 * 64];    // swizzled stride 64
    __shared__ float dpow[64], winv[64];
    const int tid = threadIdx.x, lane = tid & 63, w = tid >> 6;
    const int quad = lane >> 4, l16 = lane & 15;
    const int t0 = n * CH_;
    const int lrow = lane >> 3;
    const int lcol = ((lane & 7) ^ lrow) * 8;           // XOR-swizzled source col

    #pragma unroll
    for (int c = 0; c < 2; c++) {
        const int seg = w * 2 + c;               // 0..7, 8 rows each
        const int row = seg * 8 + lrow;
        gl2lds16(q  + ((size_t)(b * S_ + t0 + row)) * 512 + h * 64 + lcol, &QsVT[seg * 512]);
        gl2lds16(k0 + ((size_t)(t0 + row)) * 512 + h * 64 + lcol,          &KsAm[seg * 512]);
    }
    // --- FW^T combine from 4 decayed L tiles (registers -> swizzled LDS) ---
    {
        float fwacc[16] = {};
        const float dcp[4] = { 1.0f, 0.0375241f, 1.40806e-3f, 5.28365e-5f };
        #pragma unroll
        for (int jj = 1; jj <= 4; jj++) {
            const int nm = n - jj;
            if (nm < 0) break;
            const ushort* Lp = (const ushort*)(lsumsT + ((size_t)(nm * NH_ + h)) * 4096) + tid * 16;
            #pragma unroll
            for (int u = 0; u < 4; u++) {
                float f[4];
                cvt4(reinterpret_cast<const ushort4*>(Lp)[u], f);
                #pragma unroll
                for (int e = 0; e < 4; e++) fwacc[u * 4 + e] += dcp[jj - 1] * f[e];
            }
        }
        const int frow = tid >> 2;                       // FWT row (v-dim)
        #pragma unroll
        for (int half = 0; half < 2; half++) {
            const int cb = (tid & 3) * 2 + half;         // logical colblock
            union { bf16 b8v[8]; bf16x8 v; } t;
            #pragma unroll
            for (int e = 0; e < 8; e++) t.b8v[e] = f2b(fwacc[half * 8 + e]);
            *reinterpret_cast<bf16x8*>(&FWT[frow * 64 + (cb ^ (frow & 7)) * 8]) = t.v;
        }
    }
    ushort4 vreg[4];
    const int jb = (tid & 15) * 4;   // 4 consecutive v-cols
    const int sb = tid >> 4;         // s = sb + 16*it
    #pragma unroll
    for (int it = 0; it < 4; it++) {
        vreg[it] = *reinterpret_cast<const ushort4*>(
            v0 + ((size_t)(t0 + sb + it * 16)) * 512 + h * 64 + jb);
    }
    if (tid < 64) {
        dpow[tid] = powf(DECAY_, (float)tid);
        winv[tid] = wgt[(t0 + tid) * NH_ + h] * powf(DECAY_, -(float)(tid + 1));
    }
    __syncthreads();

    const int mrow = w * 16;
    float dpow_tt[4], winv_l[4];
    #pragma unroll
    for (int r = 0; r < 4; r++) dpow_tt[r] = dpow[mrow + quad * 4 + r];
    #pragma unroll
    for (int nt = 0; nt < 4; nt++) winv_l[nt] = winv[nt * 16 + l16];

    // Phase A: S = Q @ K^T (swizzled reads)
    const int cb0 = ((quad) ^ (l16 & 7)) * 8;
    const int cb1 = ((4 + quad) ^ (l16 & 7)) * 8;
    const bf16x8 af0 = *reinterpret_cast<const bf16x8*>(&QsVT[(mrow + l16) * 64 + cb0]);
    const bf16x8 af1 = *reinterpret_cast<const bf16x8*>(&QsVT[(mrow + l16) * 64 + cb1]);
    f32x4 acc[4] = {};
    #pragma unroll
    for (int nt = 0; nt < 4; nt++) {
        const bf16x8 b0 = *reinterpret_cast<const bf16x8*>(&KsAm[(nt * 16 + l16) * 64 + cb0]);
        const bf16x8 b1 = *reinterpret_cast<const bf16x8*>(&KsAm[(nt * 16 + l16) * 64 + cb1]);
        acc[nt] = __builtin_amdgcn_mfma_f32_16x16x32_bf16(af0, b0, acc[nt], 0, 0, 0);
        acc[nt] = __builtin_amdgcn_mfma_f32_16x16x32_bf16(af1, b1, acc[nt], 0, 0, 0);
    }
    __syncthreads();

    // mask + decay + gate, write Am (bf16, stride 72)
    #pragma unroll
    for (int nt = 0; nt < 4; nt++) {
        const int s = nt * 16 + l16;
        #pragma unroll
        for (int r = 0; r < 4; r++) {
            const int tt = mrow + quad * 4 + r;
            const float v = (s < tt) ? acc[nt][r] * dpow_tt[r] * winv_l[nt] : 0.f;
            KsAm[tt * 72 + s] = f2b(v);
        }
    }
    // write V^T (stride 72) from registers
    {
        ushort* VT = reinterpret_cast<ushort*>(QsVT);
        #pragma unroll
        for (int it = 0; it < 4; it++) {
            const int s = sb + it * 16;
            VT[(jb + 0) * 72 + s] = vreg[it].x;
            VT[(jb + 1) * 72 + s] = vreg[it].y;
            VT[(jb + 2) * 72 + s] = vreg[it].z;
            VT[(jb + 3) * 72 + s] = vreg[it].w;
        }
    }
    __syncthreads();

    // Phase B: O = dpow[t] * (Q @ FWT^T) + Am @ VT^T
    f32x4 o[4] = {};
    #pragma unroll
    for (int nt = 0; nt < 4; nt++) {
        const bf16x8 f0 = *reinterpret_cast<const bf16x8*>(&FWT[(nt * 16 + l16) * 64 + cb0]);
        const bf16x8 f1 = *reinterpret_cast<const bf16x8*>(&FWT[(nt * 16 + l16) * 64 + cb1]);
        o[nt] = __builtin_amdgcn_mfma_f32_16x16x32_bf16(af0, f0, o[nt], 0, 0, 0);
        o[nt] = __builtin_amdgcn_mfma_f32_16x16x32_bf16(af1, f1, o[nt], 0, 0, 0);
    }
    #pragma unroll
    for (int nt = 0; nt < 4; nt++)
        #pragma unroll
        for (int r = 0; r < 4; r++) o[nt][r] *= dpow_tt[r];

    const bf16x8 a0 = *reinterpret_cast<const bf16x8*>(&KsAm[(mrow + l16) * 72 + quad * 8]);
    const bf16x8 a1 = *reinterpret_cast<const bf16x8*>(&KsAm[(mrow + l16) * 72 + 32 + quad * 8]);
    #pragma unroll
    for (int nt = 0; nt < 4; nt++) {
        const bf16x8 v0f = *reinterpret_cast<const bf16x8*>(&QsVT[(nt * 16 + l16) * 72 + quad * 8]);
        const bf16x8 v1f = *reinterpret_cast<const bf16x8*>(&QsVT[(nt * 16 + l16) * 72 + 32 + quad * 8]);
        o[nt] = __builtin_amdgcn_mfma_f32_16x16x32_bf16(a0, v0f, o[nt], 0, 0, 0);
        o[nt] = __builtin_amdgcn_mfma_f32_16x16x32_bf16(a1, v1f, o[nt], 0, 0, 0);
    }
    #pragma unroll
    for (int nt = 0; nt < 4; nt++)
        #pragma unroll
        for (int r = 0; r < 4; r++) {
            const int tt = mrow + quad * 4 + r;
            retr[((size_t)(b * S_ + t0 + tt)) * 512 + h * 64 + nt * 16 + l16] = f2b(o[nt][r]);
        }
}

// ---------------------------------------------------------------------------
extern "C" void kernel_launch(void* const* d_in, const int* in_sizes, int n_in,
                              void* d_out, int out_size, void* d_ws, size_t ws_size,
                              hipStream_t stream) {
    const float* x  = (const float*)d_in[0];
    const float* wk = (const float*)d_in[1];
    const float* wv = (const float*)d_in[2];
    const float* wq = (const float*)d_in[3];
    const float* wg = (const float*)d_in[4];
    const float* wo = (const float*)d_in[5];
    float* out = (float*)d_out;

    const size_t MB1 = 1ull << 20;
    char* w = (char*)d_ws;
    bf16*  qbuf    = (bf16*)(w);                          // 16 MB
    bf16*  k0buf   = (bf16*)(w + 16 * MB1);               // 4 MB
    bf16*  v0buf   = (bf16*)(w + 20 * MB1);               // 4 MB
    float* wgt     = (float*)(w + 24 * MB1);              // 128 KB
    bf16*  wqb     = (bf16*)(w + 24 * MB1 + (128ull<<10));
    bf16*  wkb     = (bf16*)(w + 24 * MB1 + (128ull<<10) + 1*786432);
    bf16*  wvb     = (bf16*)(w + 24 * MB1 + (128ull<<10) + 2*786432);
    bf16*  wob     = (bf16*)(w + 24 * MB1 + (128ull<<10) + 3*786432);
    bf16*  lsumsT  = (bf16*)(w + 28 * MB1);               // 4 MB
    bf16*  retr    = (bf16*)(w + 32 * MB1);               // 16 MB
    bf16*  xb      = (bf16*)(w + 48 * MB1);               // 24 MB

    const int MB = B_ * S_;  // 16384

    // fused casts + gate (1 dispatch)
    cast_fused<<<MB + 2048, 192, 0, stream>>>(x, xb, wg, wgt,
                                              wq, wk, wv, wo, wqb, wkb, wvb, wob);

    // fused q/k/v projections (1 dispatch, XCD-strip-mapped)
    proj_fused<<<768, 256, 0, stream>>>(xb, wqb, wkb, wvb, qbuf, k0buf, v0buf);

    // chunked scan (state combine fused into chunk_output)
    chunk_sums<<<dim3(NCH_, NH_), 256, 0, stream>>>(k0buf, v0buf, wgt, lsumsT);
    chunk_output<<<dim3(NCH_, NH_, B_), 256, 0, stream>>>(qbuf, k0buf, v0buf, wgt, lsumsT, retr);

    // out = x + retrieved @ w_out^T
    gemm_out<<<dim3(D_ / 128, MB / 128), 256, 0, stream>>>(retr, wob, x, out);
}